// Round 1
// baseline (735.849 us; speedup 1.0000x reference)
//
#include <hip/hip_runtime.h>
#include <hip/hip_bf16.h>

#define ENC_DIM 2048
#define DEC_DIM 512
#define ATT_DIM 512
#define NB 256
#define NP 196
#define M_TOT (NB * NP)   // 50176 = 1568 * 32

typedef __attribute__((ext_vector_type(8))) short short8;
typedef __attribute__((ext_vector_type(4))) float f32x4;

// ---------------------------------------------------------------------------
// Kernel 1: Bt[n][k] = bf16(W_enc[k][n]); W_enc is (2048,512) row-major fp32.
// 32x32 LDS tile transpose, coalesced both sides.
// ---------------------------------------------------------------------------
__global__ __launch_bounds__(256) void prep_bt(const float* __restrict__ W,
                                               __hip_bfloat16* __restrict__ Bt) {
    __shared__ float t[32][33];
    const int k0 = blockIdx.x * 32;
    const int n0 = blockIdx.y * 32;
    const int tx = threadIdx.x;   // 0..31
    const int ty = threadIdx.y;   // 0..7
    #pragma unroll
    for (int i = 0; i < 32; i += 8)
        t[ty + i][tx] = W[(size_t)(k0 + ty + i) * ATT_DIM + n0 + tx];
    __syncthreads();
    #pragma unroll
    for (int i = 0; i < 32; i += 8)
        Bt[(size_t)(n0 + ty + i) * ENC_DIM + k0 + tx] = __float2bfloat16(t[tx][ty + i]);
}

// ---------------------------------------------------------------------------
// Kernel 2: att2f[b][n] = dec[b]@W_dec[:,n] + b_dec[n] + b_enc[n]  (fp32)
// ---------------------------------------------------------------------------
__global__ __launch_bounds__(256) void att2_kernel(const float* __restrict__ dec,
                                                   const float* __restrict__ W_dec,
                                                   const float* __restrict__ b_dec,
                                                   const float* __restrict__ b_enc,
                                                   float* __restrict__ att2f) {
    __shared__ float ds[DEC_DIM];
    const int b = blockIdx.x;
    const int t = threadIdx.x;
    ds[t]       = dec[(size_t)b * DEC_DIM + t];
    ds[t + 256] = dec[(size_t)b * DEC_DIM + t + 256];
    __syncthreads();
    #pragma unroll
    for (int j = 0; j < 2; ++j) {
        const int n = t + j * 256;
        float s = 0.f;
        #pragma unroll 8
        for (int k = 0; k < DEC_DIM; ++k)
            s += ds[k] * W_dec[(size_t)k * ATT_DIM + n];
        att2f[(size_t)b * ATT_DIM + n] = s + b_dec[n] + b_enc[n];
    }
}

// ---------------------------------------------------------------------------
// Kernel 3 (the big one): e[m] = sum_n relu(enc[m,:]@W_enc[:,n] + att2f[b,n]) * W_att[n]
// M-tile = 32 rows/block, 4 waves, wave w owns N-range [w*128, w*128+128).
// A fragments: fp32 loaded straight from global, cvt->bf16 in register.
// B fragments: contiguous short8 from Bt (L2-resident, 2 MB).
// mfma_f32_16x16x32_bf16; C/D: col=lane&15, row=(lane>>4)*4+reg (m89-verified).
// ---------------------------------------------------------------------------
__device__ __forceinline__ short8 cvt8(const float* __restrict__ p) {
    f32x4 x = *(const f32x4*)p;
    f32x4 y = *(const f32x4*)(p + 4);
    union { short8 v; __hip_bfloat16 h[8]; } u;
    u.h[0] = __float2bfloat16(x[0]);
    u.h[1] = __float2bfloat16(x[1]);
    u.h[2] = __float2bfloat16(x[2]);
    u.h[3] = __float2bfloat16(x[3]);
    u.h[4] = __float2bfloat16(y[0]);
    u.h[5] = __float2bfloat16(y[1]);
    u.h[6] = __float2bfloat16(y[2]);
    u.h[7] = __float2bfloat16(y[3]);
    return u.v;
}

__global__ __launch_bounds__(256) void e_kernel(const float* __restrict__ enc,
                                                const short* __restrict__ Bt,
                                                const float* __restrict__ att2f,
                                                const float* __restrict__ W_att,
                                                float* __restrict__ e_out) {
    const int lane = threadIdx.x & 63;
    const int wv   = threadIdx.x >> 6;   // 0..3
    const int l15  = lane & 15;
    const int kg   = lane >> 4;          // 0..3
    const int M0   = blockIdx.x * 32;

    const float* pa0 = enc + (size_t)(M0 + l15) * ENC_DIM + kg * 8;
    const float* pa1 = pa0 + (size_t)16 * ENC_DIM;
    const short* pb  = Bt + (size_t)(wv * 128 + l15) * ENC_DIM + kg * 8;

    f32x4 acc[2][8];
    #pragma unroll
    for (int i = 0; i < 2; ++i)
        #pragma unroll
        for (int j = 0; j < 8; ++j)
            acc[i][j] = (f32x4){0.f, 0.f, 0.f, 0.f};

    for (int ks = 0; ks < ENC_DIM / 32; ++ks) {
        const short8 a0 = cvt8(pa0 + ks * 32);
        const short8 a1 = cvt8(pa1 + ks * 32);
        #pragma unroll
        for (int nt = 0; nt < 8; ++nt) {
            const short8 bf = *(const short8*)(pb + (size_t)nt * 16 * ENC_DIM + ks * 32);
            acc[0][nt] = __builtin_amdgcn_mfma_f32_16x16x32_bf16(a0, bf, acc[0][nt], 0, 0, 0);
            acc[1][nt] = __builtin_amdgcn_mfma_f32_16x16x32_bf16(a1, bf, acc[1][nt], 0, 0, 0);
        }
    }

    // epilogue: + att2, relu, * W_att, reduce over n
    float wat[8];
    #pragma unroll
    for (int nt = 0; nt < 8; ++nt) wat[nt] = W_att[wv * 128 + nt * 16 + l15];

    __shared__ float ebuf[4][32];
    float ered[2][4];
    #pragma unroll
    for (int mt = 0; mt < 2; ++mt) {
        #pragma unroll
        for (int r = 0; r < 4; ++r) {
            const int m_local = mt * 16 + kg * 4 + r;
            const int bb = (M0 + m_local) / NP;
            const float* arow = att2f + (size_t)bb * ATT_DIM + wv * 128 + l15;
            float s = 0.f;
            #pragma unroll
            for (int nt = 0; nt < 8; ++nt) {
                float v = acc[mt][nt][r] + arow[nt * 16];
                v = fmaxf(v, 0.f);
                s += v * wat[nt];
            }
            s += __shfl_xor(s, 1);
            s += __shfl_xor(s, 2);
            s += __shfl_xor(s, 4);
            s += __shfl_xor(s, 8);
            ered[mt][r] = s;
        }
    }
    if (l15 == 0) {
        #pragma unroll
        for (int mt = 0; mt < 2; ++mt)
            #pragma unroll
            for (int r = 0; r < 4; ++r)
                ebuf[wv][mt * 16 + kg * 4 + r] = ered[mt][r];
    }
    __syncthreads();
    if (threadIdx.x < 32)
        e_out[M0 + threadIdx.x] = ebuf[0][threadIdx.x] + ebuf[1][threadIdx.x] +
                                  ebuf[2][threadIdx.x] + ebuf[3][threadIdx.x];
}

// ---------------------------------------------------------------------------
// Kernel 4: per-batch softmax over 196 pixels + z[b,:] = sum_p alpha[b,p]*enc[b,p,:]
// grid (256 batches, 4 column-chunks of 512), 256 threads, float2 per thread.
// ---------------------------------------------------------------------------
__global__ __launch_bounds__(256) void z_kernel(const float* __restrict__ enc,
                                                const float* __restrict__ e,
                                                float* __restrict__ z,
                                                float* __restrict__ alpha) {
    const int b  = blockIdx.x;
    const int cb = blockIdx.y;
    const int t  = threadIdx.x;
    __shared__ float al[NP];
    __shared__ float red[4];

    float ev = (t < NP) ? e[(size_t)b * NP + t] : -1e30f;
    float m = ev;
    #pragma unroll
    for (int o = 32; o > 0; o >>= 1) m = fmaxf(m, __shfl_xor(m, o));
    if ((t & 63) == 0) red[t >> 6] = m;
    __syncthreads();
    m = fmaxf(fmaxf(red[0], red[1]), fmaxf(red[2], red[3]));
    __syncthreads();
    float ex = (t < NP) ? __expf(ev - m) : 0.f;
    float s = ex;
    #pragma unroll
    for (int o = 32; o > 0; o >>= 1) s += __shfl_xor(s, o);
    if ((t & 63) == 0) red[t >> 6] = s;
    __syncthreads();
    s = red[0] + red[1] + red[2] + red[3];
    const float a = ex * (1.0f / s);
    if (t < NP) {
        al[t] = a;
        if (cb == 0) alpha[(size_t)b * NP + t] = a;
    }
    __syncthreads();

    const int c0 = cb * 512 + t * 2;
    const float2* ep = (const float2*)(enc + (size_t)b * NP * ENC_DIM + c0);
    float zx = 0.f, zy = 0.f;
    #pragma unroll 4
    for (int p = 0; p < NP; ++p) {
        const float ap = al[p];
        const float2 v = ep[(size_t)p * (ENC_DIM / 2)];
        zx += ap * v.x;
        zy += ap * v.y;
    }
    float2* zo = (float2*)(z + (size_t)b * ENC_DIM + c0);
    *zo = make_float2(zx, zy);
}

// ---------------------------------------------------------------------------
extern "C" void kernel_launch(void* const* d_in, const int* in_sizes, int n_in,
                              void* d_out, int out_size, void* d_ws, size_t ws_size,
                              hipStream_t stream) {
    const float* enc   = (const float*)d_in[0];  // (256,196,2048)
    const float* dec   = (const float*)d_in[1];  // (256,512)
    const float* W_enc = (const float*)d_in[2];  // (2048,512)
    const float* b_enc = (const float*)d_in[3];  // (512)
    const float* W_dec = (const float*)d_in[4];  // (512,512)
    const float* b_dec = (const float*)d_in[5];  // (512)
    const float* W_att = (const float*)d_in[6];  // (512,1)
    // d_in[7] = b_att: softmax-invariant, unused.

    float* z     = (float*)d_out;                 // 256*2048
    float* alpha = z + (size_t)NB * ENC_DIM;      // 256*196

    char* ws = (char*)d_ws;
    __hip_bfloat16* Bt = (__hip_bfloat16*)ws;                      // 512*2048*2 = 2 MB
    float* att2f       = (float*)(ws + 2 * 1024 * 1024);           // 256*512*4 = 512 KB
    float* e           = (float*)(ws + 2 * 1024 * 1024 + 512 * 1024); // 50176*4

    prep_bt<<<dim3(ENC_DIM / 32, ATT_DIM / 32), dim3(32, 8), 0, stream>>>(W_enc, Bt);
    att2_kernel<<<NB, 256, 0, stream>>>(dec, W_dec, b_dec, b_enc, att2f);
    e_kernel<<<M_TOT / 32, 256, 0, stream>>>(enc, (const short*)Bt, att2f, W_att, e);
    z_kernel<<<dim3(NB, 4), 256, 0, stream>>>(enc, e, z, alpha);
}

// Round 2
// 309.774 us; speedup vs baseline: 2.3754x; 2.3754x over previous
//
#include <hip/hip_runtime.h>
#include <hip/hip_bf16.h>

#define ENC_DIM 2048
#define DEC_DIM 512
#define ATT_DIM 512
#define NB 256
#define NP 196
#define M_TOT (NB * NP)   // 50176 = 784 * 64
#define BM 64
#define BK 64
#define NSTEP (ENC_DIM / BK)  // 32

typedef __attribute__((ext_vector_type(8))) short short8;
typedef __attribute__((ext_vector_type(4))) float f32x4;

// ---------------------------------------------------------------------------
// Kernel 1: pack W_enc (2048x512 fp32, row-major) into Btt bf16 tiled layout:
//   Btt[J][n][kg][8] , J = k/32 (64), n (512), kg = (k%32)/8 (4), i = k%8
// so that an MFMA B-fragment load (lane l: n=n0+l&15, kg=l>>4) is one
// fully contiguous 1 KB wave transaction.
// ---------------------------------------------------------------------------
__global__ __launch_bounds__(256) void prep_btt(const float* __restrict__ W,
                                                __hip_bfloat16* __restrict__ Btt) {
    const int gid = blockIdx.x * 256 + threadIdx.x;  // 0..131071
    const int kg = gid & 3;
    const int n  = (gid >> 2) & 511;
    const int J  = gid >> 11;
    const int k  = J * 32 + kg * 8;
    union { short8 v; __hip_bfloat16 h[8]; } u;
    #pragma unroll
    for (int i = 0; i < 8; ++i)
        u.h[i] = __float2bfloat16(W[(size_t)(k + i) * ATT_DIM + n]);
    *(short8*)((short*)Btt + (size_t)gid * 8) = u.v;
}

// ---------------------------------------------------------------------------
// Kernel 2: att2f[b][n] = dec[b]@W_dec[:,n] + b_dec[n] + b_enc[n]  (fp32)
// ---------------------------------------------------------------------------
__global__ __launch_bounds__(256) void att2_kernel(const float* __restrict__ dec,
                                                   const float* __restrict__ W_dec,
                                                   const float* __restrict__ b_dec,
                                                   const float* __restrict__ b_enc,
                                                   float* __restrict__ att2f) {
    __shared__ float ds[DEC_DIM];
    const int b = blockIdx.x;
    const int t = threadIdx.x;
    ds[t]       = dec[(size_t)b * DEC_DIM + t];
    ds[t + 256] = dec[(size_t)b * DEC_DIM + t + 256];
    __syncthreads();
    #pragma unroll
    for (int j = 0; j < 2; ++j) {
        const int n = t + j * 256;
        float s = 0.f;
        #pragma unroll 8
        for (int k = 0; k < DEC_DIM; ++k)
            s += ds[k] * W_dec[(size_t)k * ATT_DIM + n];
        att2f[(size_t)b * ATT_DIM + n] = s + b_dec[n] + b_enc[n];
    }
}

// ---------------------------------------------------------------------------
// Kernel 3: e[m] = sum_n relu(enc[m,:]@W_enc[:,n] + att2f[b,n]) * W_att[n]
// BM=64 x BN=512 per block; 8 waves, wave wv owns n-range [wv*64, wv*64+64).
// A staged in LDS as bf16 (double-buffered, XOR-swizzled), B direct from L2
// via the pre-tiled Btt (contiguous 1KB fragment loads).
// ---------------------------------------------------------------------------
__device__ __forceinline__ short8 cvt8v(f32x4 x, f32x4 y) {
    union { short8 v; __hip_bfloat16 h[8]; } u;
    u.h[0] = __float2bfloat16(x[0]);
    u.h[1] = __float2bfloat16(x[1]);
    u.h[2] = __float2bfloat16(x[2]);
    u.h[3] = __float2bfloat16(x[3]);
    u.h[4] = __float2bfloat16(y[0]);
    u.h[5] = __float2bfloat16(y[1]);
    u.h[6] = __float2bfloat16(y[2]);
    u.h[7] = __float2bfloat16(y[3]);
    return u.v;
}

__global__ __launch_bounds__(512, 4) void e_kernel(const float* __restrict__ enc,
                                                   const short* __restrict__ Btt,
                                                   const float* __restrict__ att2f,
                                                   const float* __restrict__ W_att,
                                                   float* __restrict__ e_out) {
    const int tid  = threadIdx.x;
    const int lane = tid & 63;
    const int wv   = tid >> 6;   // 0..7
    const int l15  = lane & 15;
    const int kg   = lane >> 4;  // 0..3
    const int M0   = blockIdx.x * BM;

    // [buf][kb][m ^ kb][8] bf16 : 16 KB
    __shared__ __attribute__((aligned(16))) short Asm[2][8][64][8];
    __shared__ float ebuf[8][64];

    // staging: thread stages row m_s = tid>>3, k-chunk c_s = tid&7 (8 floats)
    const int m_s = tid >> 3;
    const int c_s = tid & 7;
    const float* pa = enc + (size_t)(M0 + m_s) * ENC_DIM + c_s * 8;

    // B fragment base (shorts): full offset = step*32768 + j*16384 + nf*512 + base
    const short* pb = Btt + (wv * 64 + l15) * 32 + kg * 8;

    f32x4 acc[4][4];
    #pragma unroll
    for (int i = 0; i < 4; ++i)
        #pragma unroll
        for (int j = 0; j < 4; ++j)
            acc[i][j] = (f32x4){0.f, 0.f, 0.f, 0.f};

    // prologue: stage step 0 into buf 0
    {
        f32x4 g0 = *(const f32x4*)pa;
        f32x4 g1 = *(const f32x4*)(pa + 4);
        *(short8*)&Asm[0][c_s][m_s ^ c_s][0] = cvt8v(g0, g1);
    }

    for (int step = 0; step < NSTEP; ++step) {
        const int cur = step & 1;
        f32x4 g0, g1;
        if (step + 1 < NSTEP) {  // issue next-step A loads early (fly under MFMA)
            g0 = *(const f32x4*)(pa + (step + 1) * BK);
            g1 = *(const f32x4*)(pa + (step + 1) * BK + 4);
        }
        __syncthreads();  // buf[cur] ready; prev reads of buf[cur^1] done
        const short* pbs = pb + (size_t)step * 32768;
        #pragma unroll
        for (int j = 0; j < 2; ++j) {
            const short8 b0 = *(const short8*)(pbs + j * 16384 + 0 * 512);
            const short8 b1 = *(const short8*)(pbs + j * 16384 + 1 * 512);
            const short8 b2 = *(const short8*)(pbs + j * 16384 + 2 * 512);
            const short8 b3 = *(const short8*)(pbs + j * 16384 + 3 * 512);
            const int kb = j * 4 + kg;
            const short8 a0 = *(const short8*)&Asm[cur][kb][(0 * 16 + l15) ^ kb][0];
            const short8 a1 = *(const short8*)&Asm[cur][kb][(1 * 16 + l15) ^ kb][0];
            const short8 a2 = *(const short8*)&Asm[cur][kb][(2 * 16 + l15) ^ kb][0];
            const short8 a3 = *(const short8*)&Asm[cur][kb][(3 * 16 + l15) ^ kb][0];
            acc[0][0] = __builtin_amdgcn_mfma_f32_16x16x32_bf16(a0, b0, acc[0][0], 0, 0, 0);
            acc[0][1] = __builtin_amdgcn_mfma_f32_16x16x32_bf16(a0, b1, acc[0][1], 0, 0, 0);
            acc[0][2] = __builtin_amdgcn_mfma_f32_16x16x32_bf16(a0, b2, acc[0][2], 0, 0, 0);
            acc[0][3] = __builtin_amdgcn_mfma_f32_16x16x32_bf16(a0, b3, acc[0][3], 0, 0, 0);
            acc[1][0] = __builtin_amdgcn_mfma_f32_16x16x32_bf16(a1, b0, acc[1][0], 0, 0, 0);
            acc[1][1] = __builtin_amdgcn_mfma_f32_16x16x32_bf16(a1, b1, acc[1][1], 0, 0, 0);
            acc[1][2] = __builtin_amdgcn_mfma_f32_16x16x32_bf16(a1, b2, acc[1][2], 0, 0, 0);
            acc[1][3] = __builtin_amdgcn_mfma_f32_16x16x32_bf16(a1, b3, acc[1][3], 0, 0, 0);
            acc[2][0] = __builtin_amdgcn_mfma_f32_16x16x32_bf16(a2, b0, acc[2][0], 0, 0, 0);
            acc[2][1] = __builtin_amdgcn_mfma_f32_16x16x32_bf16(a2, b1, acc[2][1], 0, 0, 0);
            acc[2][2] = __builtin_amdgcn_mfma_f32_16x16x32_bf16(a2, b2, acc[2][2], 0, 0, 0);
            acc[2][3] = __builtin_amdgcn_mfma_f32_16x16x32_bf16(a2, b3, acc[2][3], 0, 0, 0);
            acc[3][0] = __builtin_amdgcn_mfma_f32_16x16x32_bf16(a3, b0, acc[3][0], 0, 0, 0);
            acc[3][1] = __builtin_amdgcn_mfma_f32_16x16x32_bf16(a3, b1, acc[3][1], 0, 0, 0);
            acc[3][2] = __builtin_amdgcn_mfma_f32_16x16x32_bf16(a3, b2, acc[3][2], 0, 0, 0);
            acc[3][3] = __builtin_amdgcn_mfma_f32_16x16x32_bf16(a3, b3, acc[3][3], 0, 0, 0);
        }
        if (step + 1 < NSTEP) {  // write-late into the other buffer
            *(short8*)&Asm[cur ^ 1][c_s][m_s ^ c_s][0] = cvt8v(g0, g1);
        }
    }

    // epilogue: + att2, relu, * W_att, reduce over n
    float wat[4];
    #pragma unroll
    for (int nf = 0; nf < 4; ++nf) wat[nf] = W_att[wv * 64 + nf * 16 + l15];

    #pragma unroll
    for (int mf = 0; mf < 4; ++mf) {
        #pragma unroll
        for (int r = 0; r < 4; ++r) {
            const int ml = mf * 16 + kg * 4 + r;       // local row
            const int bb = (M0 + ml) / NP;             // batch of this row
            const float* arow = att2f + (size_t)bb * ATT_DIM + wv * 64 + l15;
            float s = 0.f;
            #pragma unroll
            for (int nf = 0; nf < 4; ++nf) {
                float v = acc[mf][nf][r] + arow[nf * 16];
                s += fmaxf(v, 0.f) * wat[nf];
            }
            s += __shfl_xor(s, 1);
            s += __shfl_xor(s, 2);
            s += __shfl_xor(s, 4);
            s += __shfl_xor(s, 8);
            if (l15 == 0) ebuf[wv][ml] = s;
        }
    }
    __syncthreads();
    if (tid < 64) {
        float s = 0.f;
        #pragma unroll
        for (int w = 0; w < 8; ++w) s += ebuf[w][tid];
        e_out[M0 + tid] = s;
    }
}

// ---------------------------------------------------------------------------
// Kernel 4: per-batch softmax over 196 pixels + z[b,:] = sum_p alpha[b,p]*enc[b,p,:]
// grid (256, 2): 1024-col chunks, float4 per thread.
// ---------------------------------------------------------------------------
__global__ __launch_bounds__(256) void z_kernel(const float* __restrict__ enc,
                                                const float* __restrict__ e,
                                                float* __restrict__ z,
                                                float* __restrict__ alpha) {
    const int b  = blockIdx.x;
    const int cb = blockIdx.y;
    const int t  = threadIdx.x;
    __shared__ float al[NP];
    __shared__ float red[4];

    float ev = (t < NP) ? e[(size_t)b * NP + t] : -1e30f;
    float m = ev;
    #pragma unroll
    for (int o = 32; o > 0; o >>= 1) m = fmaxf(m, __shfl_xor(m, o));
    if ((t & 63) == 0) red[t >> 6] = m;
    __syncthreads();
    m = fmaxf(fmaxf(red[0], red[1]), fmaxf(red[2], red[3]));
    __syncthreads();
    float ex = (t < NP) ? __expf(ev - m) : 0.f;
    float s = ex;
    #pragma unroll
    for (int o = 32; o > 0; o >>= 1) s += __shfl_xor(s, o);
    if ((t & 63) == 0) red[t >> 6] = s;
    __syncthreads();
    s = red[0] + red[1] + red[2] + red[3];
    const float a = ex * (1.0f / s);
    if (t < NP) {
        al[t] = a;
        if (cb == 0) alpha[(size_t)b * NP + t] = a;
    }
    __syncthreads();

    const int c0 = cb * 1024 + t * 4;
    const float4* ep = (const float4*)(enc + (size_t)b * NP * ENC_DIM + c0);
    float4 zv = make_float4(0.f, 0.f, 0.f, 0.f);
    #pragma unroll 4
    for (int p = 0; p < NP; ++p) {
        const float ap = al[p];
        const float4 v = ep[(size_t)p * (ENC_DIM / 4)];
        zv.x += ap * v.x;
        zv.y += ap * v.y;
        zv.z += ap * v.z;
        zv.w += ap * v.w;
    }
    *(float4*)(z + (size_t)b * ENC_DIM + c0) = zv;
}

// ---------------------------------------------------------------------------
extern "C" void kernel_launch(void* const* d_in, const int* in_sizes, int n_in,
                              void* d_out, int out_size, void* d_ws, size_t ws_size,
                              hipStream_t stream) {
    const float* enc   = (const float*)d_in[0];  // (256,196,2048)
    const float* dec   = (const float*)d_in[1];  // (256,512)
    const float* W_enc = (const float*)d_in[2];  // (2048,512)
    const float* b_enc = (const float*)d_in[3];  // (512)
    const float* W_dec = (const float*)d_in[4];  // (512,512)
    const float* b_dec = (const float*)d_in[5];  // (512)
    const float* W_att = (const float*)d_in[6];  // (512,1)
    // d_in[7] = b_att: softmax-invariant, unused.

    float* z     = (float*)d_out;                 // 256*2048
    float* alpha = z + (size_t)NB * ENC_DIM;      // 256*196

    char* ws = (char*)d_ws;
    __hip_bfloat16* Btt = (__hip_bfloat16*)ws;                        // 2 MB
    float* att2f        = (float*)(ws + 2 * 1024 * 1024);             // 512 KB
    float* e            = (float*)(ws + 2 * 1024 * 1024 + 512 * 1024);// 200 KB

    prep_btt<<<512, 256, 0, stream>>>(W_enc, Btt);
    att2_kernel<<<NB, 256, 0, stream>>>(dec, W_dec, b_dec, b_enc, att2f);
    e_kernel<<<M_TOT / BM, 512, 0, stream>>>(enc, (const short*)Btt, att2f, W_att, e);
    z_kernel<<<dim3(NB, 2), 256, 0, stream>>>(enc, e, z, alpha);
}